// Round 1
// baseline (3090.167 us; speedup 1.0000x reference)
//
#include <hip/hip_runtime.h>
#include <cstdint>

// Problem constants
constexpr int B_    = 4;
constexpr int NIN_  = 50000;
constexpr int NOUT_ = 50000;
constexpr int E_    = 819200;
constexpr int CI    = 16;
constexpr int CO    = 16;
constexpr int Hh    = 100;

constexpr int TILE = 64;    // edges per block
constexpr int HP   = 101;   // padded hidden stride (101 mod 32 = 5, gcd(5,32)=1 -> 2-way LDS, free)
constexpr int WST  = 65;    // W_chunk stride (65 mod 32 = 1 -> 2-way, free)
constexpr int JW   = 25;    // hidden outputs per wave (4 waves x 25 = 100)

// One block = 256 threads = 4 waves, processes TILE=64 edges.
// wave w computes hidden slice j in [w*25, w*25+25) -> weight indices wave-uniform (s_load).
// Layer4+message: 4 io-chunks of 64; phase A computes W chunk into LDS, phase B (wave=batch)
// accumulates msg[16] in registers; final global atomicAdd scatter.
__global__ __launch_bounds__(256)
void edge_kernel(const float* __restrict__ x,
                 const float* __restrict__ ipos,
                 const float* __restrict__ opos,
                 const int*   __restrict__ esrc,
                 const int*   __restrict__ edst,
                 const float* __restrict__ w1, const float* __restrict__ b1,
                 const float* __restrict__ w2, const float* __restrict__ b2,
                 const float* __restrict__ w3, const float* __restrict__ b3,
                 const float* __restrict__ w4, const float* __restrict__ b4,
                 float* __restrict__ agg, float* __restrict__ deg)
{
    __shared__ float hA[TILE * HP];   // h1, then h3
    __shared__ float hB[TILE * HP];   // attr, then h2, then W chunks (64*65 = 4160 floats, fits)
    __shared__ int s_src[TILE];
    __shared__ int s_dst[TILE];

    const int tid  = threadIdx.x;
    const int wv   = __builtin_amdgcn_readfirstlane(tid >> 6);  // force wave-uniform
    const int lane = tid & 63;
    const int e0   = blockIdx.x * TILE;

    // --- load edge indices + edge attributes (first 64 threads) ---
    if (tid < TILE) {
        int s = esrc[e0 + tid];
        int d = edst[e0 + tid];
        s_src[tid] = s;
        s_dst[tid] = d;
        // e_attr = [out_pos[dst] (3), inp_pos[src] (3)]
        hB[tid * HP + 0] = opos[d * 3 + 0];
        hB[tid * HP + 1] = opos[d * 3 + 1];
        hB[tid * HP + 2] = opos[d * 3 + 2];
        hB[tid * HP + 3] = ipos[s * 3 + 0];
        hB[tid * HP + 4] = ipos[s * 3 + 1];
        hB[tid * HP + 5] = ipos[s * 3 + 2];
    }
    __syncthreads();

    const int j0 = wv * JW;

    // --- layer 1: hA = relu(attr @ w1 + b1), attr in hB[:,0:6] ---
    {
        float acc[JW];
        #pragma unroll
        for (int jj = 0; jj < JW; ++jj) acc[jj] = b1[j0 + jj];
        #pragma unroll
        for (int k = 0; k < 6; ++k) {
            float hk = hB[lane * HP + k];
            #pragma unroll
            for (int jj = 0; jj < JW; ++jj)
                acc[jj] = fmaf(hk, w1[k * Hh + j0 + jj], acc[jj]);
        }
        #pragma unroll
        for (int jj = 0; jj < JW; ++jj)
            hA[lane * HP + j0 + jj] = fmaxf(acc[jj], 0.f);
    }
    __syncthreads();

    // --- layer 2: hB = relu(hA @ w2 + b2) ---
    {
        float acc[JW];
        #pragma unroll
        for (int jj = 0; jj < JW; ++jj) acc[jj] = b2[j0 + jj];
        #pragma unroll 4
        for (int k = 0; k < Hh; ++k) {
            float hk = hA[lane * HP + k];
            #pragma unroll
            for (int jj = 0; jj < JW; ++jj)
                acc[jj] = fmaf(hk, w2[k * Hh + j0 + jj], acc[jj]);
        }
        #pragma unroll
        for (int jj = 0; jj < JW; ++jj)
            hB[lane * HP + j0 + jj] = fmaxf(acc[jj], 0.f);
    }
    __syncthreads();

    // --- layer 3: hA = relu(hB @ w3 + b3) ---
    {
        float acc[JW];
        #pragma unroll
        for (int jj = 0; jj < JW; ++jj) acc[jj] = b3[j0 + jj];
        #pragma unroll 4
        for (int k = 0; k < Hh; ++k) {
            float hk = hB[lane * HP + k];
            #pragma unroll
            for (int jj = 0; jj < JW; ++jj)
                acc[jj] = fmaf(hk, w3[k * Hh + j0 + jj], acc[jj]);
        }
        #pragma unroll
        for (int jj = 0; jj < JW; ++jj)
            hA[lane * HP + j0 + jj] = fmaxf(acc[jj], 0.f);
    }
    __syncthreads();

    // --- layer 4 + message. h3 in hA. wave = batch b, lane = edge. ---
    const int mysrc = s_src[lane];
    const int mydst = s_dst[lane];

    // preload x[b=wv, src, :]  (16 floats, 4x float4, 16B-aligned)
    float xv[CI];
    #pragma unroll
    for (int i = 0; i < CI; i += 4) {
        float4 v = *reinterpret_cast<const float4*>(
            &x[(size_t)wv * (NIN_ * CI) + (size_t)mysrc * CI + i]);
        xv[i] = v.x; xv[i + 1] = v.y; xv[i + 2] = v.z; xv[i + 3] = v.w;
    }

    float macc[CO];
    #pragma unroll
    for (int o = 0; o < CO; ++o) macc[o] = 0.f;

    for (int ch = 0; ch < 4; ++ch) {
        // phase A: W_chunk[e][c] for io = ch*64 + c; this thread: e=lane, c in [wv*16, wv*16+16)
        const int io0 = ch * 64 + wv * 16;
        float acc[16];
        #pragma unroll
        for (int c = 0; c < 16; ++c) acc[c] = b4[io0 + c];
        #pragma unroll 4
        for (int k = 0; k < Hh; ++k) {
            float hk = hA[lane * HP + k];
            #pragma unroll
            for (int c = 0; c < 16; ++c)
                acc[c] = fmaf(hk, w4[k * 256 + io0 + c], acc[c]);
        }
        #pragma unroll
        for (int c = 0; c < 16; ++c)
            hB[lane * WST + wv * 16 + c] = acc[c];
        __syncthreads();

        // phase B: msg accumulation for b=wv, e=lane
        #pragma unroll
        for (int c = 0; c < 64; ++c) {
            const int i = ch * 4 + (c >> 4);
            const int o = c & 15;
            macc[o] = fmaf(xv[i], hB[lane * WST + c], macc[o]);
        }
        __syncthreads();   // protect W chunk before next phase A overwrites
    }

    // --- scatter: agg[n][b][o] += msg, deg[n] += 1 ---
    float* aggp = agg + (size_t)mydst * (B_ * CO) + wv * CO;
    #pragma unroll
    for (int o = 0; o < CO; ++o)
        atomicAdd(&aggp[o], macc[o]);
    if (wv == 0)
        atomicAdd(&deg[mydst], 1.0f);
}

// out[b][n][o] = agg[n][b][o] / max(deg[n],1) + bias[o]
__global__ __launch_bounds__(256)
void finalize_kernel(const float* __restrict__ agg,
                     const float* __restrict__ deg,
                     const float* __restrict__ bias,
                     float* __restrict__ out)
{
    const int idx = blockIdx.x * 256 + threadIdx.x;   // over B*NOUT*CO = 3.2M
    if (idx >= B_ * NOUT_ * CO) return;
    const int o = idx & 15;
    const int n = (idx >> 4) % NOUT_;
    const int b = idx / (NOUT_ * CO);
    const float d = fmaxf(deg[n], 1.0f);
    out[idx] = agg[(size_t)n * (B_ * CO) + b * CO + o] / d + bias[o];
}

extern "C" void kernel_launch(void* const* d_in, const int* in_sizes, int n_in,
                              void* d_out, int out_size, void* d_ws, size_t ws_size,
                              hipStream_t stream)
{
    const float* x    = (const float*)d_in[0];
    const float* ipos = (const float*)d_in[1];
    const float* opos = (const float*)d_in[2];
    const int*   esrc = (const int*)d_in[3];
    const int*   edst = (const int*)d_in[4];
    const float* w1   = (const float*)d_in[5];
    const float* b1   = (const float*)d_in[6];
    const float* w2   = (const float*)d_in[7];
    const float* b2   = (const float*)d_in[8];
    const float* w3   = (const float*)d_in[9];
    const float* b3   = (const float*)d_in[10];
    const float* w4   = (const float*)d_in[11];
    const float* b4   = (const float*)d_in[12];
    // d_in[13] = root (unused by reference)
    const float* bias = (const float*)d_in[14];

    float* agg = (float*)d_ws;                        // NOUT * B * CO = 3.2M floats
    float* deg = agg + (size_t)NOUT_ * (B_ * CO);     // NOUT floats

    // d_ws is poisoned 0xAA before every launch -> zero the accumulators
    hipMemsetAsync(d_ws, 0,
                   ((size_t)NOUT_ * (B_ * CO) + NOUT_) * sizeof(float), stream);

    edge_kernel<<<E_ / TILE, 256, 0, stream>>>(
        x, ipos, opos, esrc, edst,
        w1, b1, w2, b2, w3, b3, w4, b4,
        agg, deg);

    const int total = B_ * NOUT_ * CO;
    finalize_kernel<<<(total + 255) / 256, 256, 0, stream>>>(agg, deg, bias,
                                                             (float*)d_out);
}

// Round 2
// 656.446 us; speedup vs baseline: 4.7074x; 4.7074x over previous
//
#include <hip/hip_runtime.h>
#include <cstdint>

constexpr int B_    = 4;
constexpr int NIN_  = 50000;
constexpr int NOUT_ = 50000;
constexpr int E_    = 819200;
constexpr int CI    = 16;
constexpr int CO    = 16;
constexpr int Hh    = 100;

constexpr int TILE = 64;     // edges per block
constexpr int KP   = 128;    // padded hidden dim (K and N for layers 2/3)

typedef __attribute__((ext_vector_type(8))) short bf16x8;
typedef __attribute__((ext_vector_type(4))) float f32x4;

__device__ __host__ inline unsigned short f2bf(float f) {
    union { float f; unsigned u; } v; v.f = f;
    unsigned r = v.u + 0x7FFF + ((v.u >> 16) & 1);   // RNE
    return (unsigned short)(r >> 16);
}

// Element-index swizzle within a row of 128 bf16 (256 B): permutes 16B chunks.
// chunk' = chunk ^ (r&7) ^ ((r&8)>>2)  -> expressed at element granularity.
__device__ inline int swz(int r, int k) {
    return r * KP + (k ^ (((r & 7) << 3) ^ ((r & 8) << 1)));
}

// ---------------- prep: padded transposed bf16 weights + padded biases ------
__global__ __launch_bounds__(256)
void prep_kernel(const float* __restrict__ w2, const float* __restrict__ w3,
                 const float* __restrict__ w4, const float* __restrict__ b2,
                 const float* __restrict__ b3, const float* __restrict__ b4,
                 unsigned short* __restrict__ W2T, unsigned short* __restrict__ W3T,
                 unsigned short* __restrict__ W4T,
                 float* __restrict__ b2p, float* __restrict__ b3p,
                 float* __restrict__ b4p)
{
    int i = blockIdx.x * 256 + threadIdx.x;
    if (i < 16384) {                       // W2T[n][k] = w2[k][n], 128x128
        int n = i >> 7, k = i & 127;
        W2T[i] = (n < Hh && k < Hh) ? f2bf(w2[k * Hh + n]) : (unsigned short)0;
    } else if (i < 32768) {                // W3T
        int j = i - 16384; int n = j >> 7, k = j & 127;
        W3T[j] = (n < Hh && k < Hh) ? f2bf(w3[k * Hh + n]) : (unsigned short)0;
    } else if (i < 65536) {                // W4T[n][k] = w4[k][n], 256x128
        int j = i - 32768; int n = j >> 7, k = j & 127;
        W4T[j] = (k < Hh) ? f2bf(w4[k * 256 + n]) : (unsigned short)0;
    } else if (i < 65664) {
        int j = i - 65536; b2p[j] = (j < Hh) ? b2[j] : 0.f;
    } else if (i < 65792) {
        int j = i - 65664; b3p[j] = (j < Hh) ? b3[j] : 0.f;
    } else if (i < 66048) {
        int j = i - 65792; b4p[j] = b4[j];
    }
}

// ---------------- MFMA hidden layer (relu(src @ W + b)) --------------------
// wave wv owns N-tiles {2wv, 2wv+1}; B-frags held in regs across the 4 M-tiles.
__device__ inline void mfma_layer(const unsigned short* __restrict__ WT,
                                  const float* __restrict__ bp,
                                  const unsigned short* __restrict__ src,
                                  unsigned short* __restrict__ dst,
                                  int wv, int lane)
{
    const int cl = lane & 15;       // column within tile / A-row within tile
    const int kg = lane >> 4;       // k-group (8 contiguous bf16)
    #pragma unroll
    for (int t = 0; t < 2; ++t) {
        const int nt = wv * 2 + t;
        const unsigned short* wrow = WT + (nt * 16 + cl) * KP + kg * 8;
        bf16x8 bf[4];
        #pragma unroll
        for (int ks = 0; ks < 4; ++ks)
            bf[ks] = *reinterpret_cast<const bf16x8*>(wrow + ks * 32);
        const float bv = bp[nt * 16 + cl];
        #pragma unroll
        for (int mt = 0; mt < 4; ++mt) {
            f32x4 acc = {bv, bv, bv, bv};
            const int row = mt * 16 + cl;
            #pragma unroll
            for (int ks = 0; ks < 4; ++ks) {
                bf16x8 af = *reinterpret_cast<const bf16x8*>(
                    &src[swz(row, ks * 32 + kg * 8)]);
                acc = __builtin_amdgcn_mfma_f32_16x16x32_bf16(af, bf[ks], acc, 0, 0, 0);
            }
            // D: row = mt*16 + kg*4 + j, col = nt*16 + cl
            #pragma unroll
            for (int j = 0; j < 4; ++j)
                dst[swz(mt * 16 + kg * 4 + j, nt * 16 + cl)] =
                    f2bf(fmaxf(acc[j], 0.f));
        }
    }
}

// ---------------- main fused kernel ----------------------------------------
__global__ __launch_bounds__(256)
void edge_kernel(const float* __restrict__ x, const float* __restrict__ ipos,
                 const float* __restrict__ opos, const int* __restrict__ esrc,
                 const int* __restrict__ edst,
                 const float* __restrict__ w1, const float* __restrict__ b1,
                 const unsigned short* __restrict__ W2T,
                 const unsigned short* __restrict__ W3T,
                 const unsigned short* __restrict__ W4T,
                 const float* __restrict__ b2p, const float* __restrict__ b3p,
                 const float* __restrict__ b4p,
                 float* __restrict__ agg, float* __restrict__ deg)
{
    __shared__ unsigned short hA[TILE * KP];   // 16 KB
    __shared__ unsigned short hB[TILE * KP];   // 16 KB
    __shared__ float xs[TILE * 69];            // x gathered, [e][b*17+i], 17.7 KB
    __shared__ float s_attr[TILE * 9];         // 2.3 KB
    __shared__ int s_src[TILE], s_dst[TILE];

    const int tid  = threadIdx.x;
    const int wv   = __builtin_amdgcn_readfirstlane(tid >> 6);
    const int lane = tid & 63;
    const int e0   = blockIdx.x * TILE;

    if (tid < TILE) {
        int s = esrc[e0 + tid];
        int d = edst[e0 + tid];
        s_src[tid] = s; s_dst[tid] = d;
        s_attr[tid * 9 + 0] = opos[d * 3 + 0];
        s_attr[tid * 9 + 1] = opos[d * 3 + 1];
        s_attr[tid * 9 + 2] = opos[d * 3 + 2];
        s_attr[tid * 9 + 3] = ipos[s * 3 + 0];
        s_attr[tid * 9 + 4] = ipos[s * 3 + 1];
        s_attr[tid * 9 + 5] = ipos[s * 3 + 2];
        atomicAdd(&deg[d], 1.0f);
    }
    __syncthreads();

    // ---- x gather (issue early) + layer 1 (fp32 VALU, K=6) ----
    {
        const int src = s_src[lane];
        const float* xp = x + ((size_t)wv * NIN_ + src) * CI;
        float4 xq[4];
        #pragma unroll
        for (int q = 0; q < 4; ++q)
            xq[q] = *reinterpret_cast<const float4*>(xp + q * 4);

        float acc1[32];
        const int c0 = wv * 32;
        #pragma unroll
        for (int cc = 0; cc < 32; ++cc) {
            int c = c0 + cc;
            acc1[cc] = (c < Hh) ? b1[c] : 0.f;
        }
        #pragma unroll
        for (int k = 0; k < 6; ++k) {
            float a = s_attr[lane * 9 + k];
            #pragma unroll
            for (int cc = 0; cc < 32; ++cc) {
                int c = c0 + cc;
                float w = (c < Hh) ? w1[k * Hh + c] : 0.f;
                acc1[cc] = fmaf(a, w, acc1[cc]);
            }
        }
        #pragma unroll
        for (int cc = 0; cc < 32; cc += 2) {
            unsigned lo = f2bf(fmaxf(acc1[cc], 0.f));
            unsigned hi = f2bf(fmaxf(acc1[cc + 1], 0.f));
            *reinterpret_cast<unsigned*>(&hA[swz(lane, c0 + cc)]) = lo | (hi << 16);
        }
        #pragma unroll
        for (int q = 0; q < 4; ++q) {
            xs[lane * 69 + wv * 17 + q * 4 + 0] = xq[q].x;
            xs[lane * 69 + wv * 17 + q * 4 + 1] = xq[q].y;
            xs[lane * 69 + wv * 17 + q * 4 + 2] = xq[q].z;
            xs[lane * 69 + wv * 17 + q * 4 + 3] = xq[q].w;
        }
    }
    __syncthreads();

    mfma_layer(W2T, b2p, hA, hB, wv, lane);
    __syncthreads();
    mfma_layer(W3T, b3p, hB, hA, wv, lane);
    __syncthreads();

    // ---- layer 4 + fused message + scatter ----
    // wave wv owns edges [wv*16, wv*16+16); N-tile nt == input channel i,
    // D-col == output channel o.
    {
        const int cl = lane & 15;
        const int kg = lane >> 4;
        bf16x8 af4[4];
        {
            const int row = wv * 16 + cl;
            #pragma unroll
            for (int ks = 0; ks < 4; ++ks)
                af4[ks] = *reinterpret_cast<const bf16x8*>(
                    &hA[swz(row, ks * 32 + kg * 8)]);
        }
        float macc[16];   // [b][j]
        #pragma unroll
        for (int q = 0; q < 16; ++q) macc[q] = 0.f;

        #pragma unroll 4
        for (int nt = 0; nt < 16; ++nt) {
            const unsigned short* wrow = W4T + (nt * 16 + cl) * KP + kg * 8;
            const float bv = b4p[nt * 16 + cl];
            f32x4 acc = {bv, bv, bv, bv};
            #pragma unroll
            for (int ks = 0; ks < 4; ++ks) {
                bf16x8 bfr = *reinterpret_cast<const bf16x8*>(wrow + ks * 32);
                acc = __builtin_amdgcn_mfma_f32_16x16x32_bf16(af4[ks], bfr, acc, 0, 0, 0);
            }
            #pragma unroll
            for (int j = 0; j < 4; ++j) {
                const int e = wv * 16 + kg * 4 + j;
                const float* xrow = &xs[e * 69 + nt];
                #pragma unroll
                for (int b = 0; b < 4; ++b)
                    macc[b * 4 + j] = fmaf(xrow[b * 17], acc[j], macc[b * 4 + j]);
            }
        }
        #pragma unroll
        for (int j = 0; j < 4; ++j) {
            const int e = wv * 16 + kg * 4 + j;
            float* p = agg + (size_t)s_dst[e] * (B_ * CO) + cl;
            #pragma unroll
            for (int b = 0; b < 4; ++b)
                atomicAdd(p + b * 16, macc[b * 4 + j]);
        }
    }
}

// out[b][n][o] = agg[n][b][o] / max(deg[n],1) + bias[o]
__global__ __launch_bounds__(256)
void finalize_kernel(const float* __restrict__ agg, const float* __restrict__ deg,
                     const float* __restrict__ bias, float* __restrict__ out)
{
    const int idx = blockIdx.x * 256 + threadIdx.x;
    if (idx >= B_ * NOUT_ * CO) return;
    const int o = idx & 15;
    const int n = (idx >> 4) % NOUT_;
    const int b = idx / (NOUT_ * CO);
    const float d = fmaxf(deg[n], 1.0f);
    out[idx] = agg[(size_t)n * (B_ * CO) + b * CO + o] / d + bias[o];
}

extern "C" void kernel_launch(void* const* d_in, const int* in_sizes, int n_in,
                              void* d_out, int out_size, void* d_ws, size_t ws_size,
                              hipStream_t stream)
{
    const float* x    = (const float*)d_in[0];
    const float* ipos = (const float*)d_in[1];
    const float* opos = (const float*)d_in[2];
    const int*   esrc = (const int*)d_in[3];
    const int*   edst = (const int*)d_in[4];
    const float* w1   = (const float*)d_in[5];
    const float* b1   = (const float*)d_in[6];
    const float* w2   = (const float*)d_in[7];
    const float* b2   = (const float*)d_in[8];
    const float* w3   = (const float*)d_in[9];
    const float* b3   = (const float*)d_in[10];
    const float* w4   = (const float*)d_in[11];
    const float* b4   = (const float*)d_in[12];
    // d_in[13] = root (unused by reference)
    const float* bias = (const float*)d_in[14];

    // Scratch weights live in d_out's first 133 KB; finalize overwrites them.
    char* ob = (char*)d_out;
    unsigned short* W2T = (unsigned short*)(ob);            // 32 KB
    unsigned short* W3T = (unsigned short*)(ob + 32768);    // 32 KB
    unsigned short* W4T = (unsigned short*)(ob + 65536);    // 64 KB
    float* b2p = (float*)(ob + 131072);
    float* b3p = (float*)(ob + 131584);
    float* b4p = (float*)(ob + 132096);                     // ends at 133120 B

    float* agg = (float*)d_ws;                              // 3.2M floats
    float* deg = agg + (size_t)NOUT_ * (B_ * CO);           // 50000 floats

    hipMemsetAsync(d_ws, 0,
                   ((size_t)NOUT_ * (B_ * CO) + NOUT_) * sizeof(float), stream);

    prep_kernel<<<258, 256, 0, stream>>>(w2, w3, w4, b2, b3, b4,
                                         W2T, W3T, W4T, b2p, b3p, b4p);

    edge_kernel<<<E_ / TILE, 256, 0, stream>>>(
        x, ipos, opos, esrc, edst, w1, b1,
        W2T, W3T, W4T, b2p, b3p, b4p, agg, deg);

    const int total = B_ * NOUT_ * CO;
    finalize_kernel<<<(total + 255) / 256, 256, 0, stream>>>(agg, deg, bias,
                                                             (float*)d_out);
}